// Round 2
// baseline (269.732 us; speedup 1.0000x reference)
//
#include <hip/hip_runtime.h>

#define NEG_SLOPE 0.2f
#define D 64

typedef float f32x4 __attribute__((ext_vector_type(4)));   // native clang vector: OK for nontemporal builtins

// Kernel 1: s1[i] = Wh[i,:] . a[:64],  s2[i] = Wh[i,:] . a[64:]
// One 64-lane wave per row. Lane k handles element k (coalesced loads).
__global__ __launch_bounds__(256) void gemv2_kernel(const float* __restrict__ Wh,
                                                    const float* __restrict__ a,
                                                    float* __restrict__ s,  // s[0..N)=s1, s[N..2N)=s2
                                                    int N) {
    const int gtid = blockIdx.x * blockDim.x + threadIdx.x;
    const int row  = gtid >> 6;          // wave index
    const int lane = threadIdx.x & 63;
    if (row >= N) return;

    const float w  = Wh[row * D + lane];
    float sum1 = w * a[lane];
    float sum2 = w * a[D + lane];

    #pragma unroll
    for (int off = 32; off > 0; off >>= 1) {
        sum1 += __shfl_down(sum1, off, 64);
        sum2 += __shfl_down(sum2, off, 64);
    }
    if (lane == 0) {
        s[row]     = sum1;
        s[N + row] = sum2;
    }
}

// Kernel 2: out[i][j] = leaky_relu(s1[i] + s2[j]).
// One block per row. 256 threads x 8 float4 = 8192 floats = one full row.
// Pure streaming write: nontemporal float4 stores (out is written once, never read),
// s2 row (32 KB) stays temporal -> L1/L2 resident across all 8192 blocks.
__global__ __launch_bounds__(256) void expand_kernel(const float* __restrict__ s,
                                                     float* __restrict__ out,
                                                     int N) {
    const int row = blockIdx.x;
    const float s1 = s[row];                                  // wave-uniform, scalarized
    const f32x4* __restrict__ s2v = reinterpret_cast<const f32x4*>(s + N);
    f32x4* __restrict__ o = reinterpret_cast<f32x4*>(out) + (size_t)row * (size_t)(N >> 2);
    const int n4 = N >> 2;                                    // 2048 float4 per row

    #pragma unroll 8
    for (int c = threadIdx.x; c < n4; c += 256) {
        const f32x4 v = s2v[c];
        f32x4 e = s1 + v;                                     // vector broadcast add
        // leaky relu, elementwise
        e.x = (e.x >= 0.f) ? e.x : NEG_SLOPE * e.x;
        e.y = (e.y >= 0.f) ? e.y : NEG_SLOPE * e.y;
        e.z = (e.z >= 0.f) ? e.z : NEG_SLOPE * e.z;
        e.w = (e.w >= 0.f) ? e.w : NEG_SLOPE * e.w;
        __builtin_nontemporal_store(e, &o[c]);
    }
}

extern "C" void kernel_launch(void* const* d_in, const int* in_sizes, int n_in,
                              void* d_out, int out_size, void* d_ws, size_t ws_size,
                              hipStream_t stream) {
    const float* Wh = (const float*)d_in[0];   // (N, 64) fp32
    const float* a  = (const float*)d_in[1];   // (128, 1) fp32
    float* out = (float*)d_out;                // (N, N) fp32
    float* s   = (float*)d_ws;                 // 2N floats of scratch

    const int N = in_sizes[0] / D;             // 8192

    // Kernel 1: N waves -> N*64 threads, 256-thread blocks (4 waves/block)
    {
        const int threads = 256;
        const int blocks  = (N * 64 + threads - 1) / threads;
        gemv2_kernel<<<blocks, threads, 0, stream>>>(Wh, a, s, N);
    }

    // Kernel 2: one block per row
    {
        expand_kernel<<<N, 256, 0, stream>>>(s, out, N);
    }
}

// Round 3
// 251.588 us; speedup vs baseline: 1.0721x; 1.0721x over previous
//
#include <hip/hip_runtime.h>

#define NEG_SLOPE 0.2f
#define D 64

// Kernel 1: s1[i] = Wh[i,:] . a[:64],  s2[i] = Wh[i,:] . a[64:]
// One 64-lane wave per row. Lane k handles element k (coalesced loads).
__global__ __launch_bounds__(256) void gemv2_kernel(const float* __restrict__ Wh,
                                                    const float* __restrict__ a,
                                                    float* __restrict__ s,  // s[0..N)=s1, s[N..2N)=s2
                                                    int N) {
    const int gtid = blockIdx.x * blockDim.x + threadIdx.x;
    const int row  = gtid >> 6;          // wave index
    const int lane = threadIdx.x & 63;
    if (row >= N) return;

    const float w  = Wh[row * D + lane];
    float sum1 = w * a[lane];
    float sum2 = w * a[D + lane];

    #pragma unroll
    for (int off = 32; off > 0; off >>= 1) {
        sum1 += __shfl_down(sum1, off, 64);
        sum2 += __shfl_down(sum2, off, 64);
    }
    if (lane == 0) {
        s[row]     = sum1;
        s[N + row] = sum2;
    }
}

// Kernel 2: out[i][j] = leaky_relu(s1[i] + s2[j]). One float4 per thread.
// Proven-fastest structure (round 0, 252.5 us): temporal stores, grid (N/4/256, N).
__global__ __launch_bounds__(256) void expand_kernel(const float* __restrict__ s,
                                                     float* __restrict__ out,
                                                     int N) {
    const int row = blockIdx.y;
    const int c4  = blockIdx.x * blockDim.x + threadIdx.x;   // float4 column index
    const float s1 = s[row];
    const float4 s2 = reinterpret_cast<const float4*>(s + N)[c4];

    float4 e;
    e.x = s1 + s2.x;
    e.y = s1 + s2.y;
    e.z = s1 + s2.z;
    e.w = s1 + s2.w;
    e.x = (e.x >= 0.f) ? e.x : NEG_SLOPE * e.x;
    e.y = (e.y >= 0.f) ? e.y : NEG_SLOPE * e.y;
    e.z = (e.z >= 0.f) ? e.z : NEG_SLOPE * e.z;
    e.w = (e.w >= 0.f) ? e.w : NEG_SLOPE * e.w;

    reinterpret_cast<float4*>(out)[(size_t)row * (N >> 2) + c4] = e;
}

extern "C" void kernel_launch(void* const* d_in, const int* in_sizes, int n_in,
                              void* d_out, int out_size, void* d_ws, size_t ws_size,
                              hipStream_t stream) {
    const float* Wh = (const float*)d_in[0];   // (N, 64) fp32
    const float* a  = (const float*)d_in[1];   // (128, 1) fp32
    float* out = (float*)d_out;                // (N, N) fp32
    float* s   = (float*)d_ws;                 // 2N floats of scratch

    const int N = in_sizes[0] / D;             // 8192

    // Kernel 1: N waves -> N*64 threads, 256-thread blocks (4 waves/block)
    {
        const int threads = 256;
        const int blocks  = (N * 64 + threads - 1) / threads;
        gemv2_kernel<<<blocks, threads, 0, stream>>>(Wh, a, s, N);
    }

    // Kernel 2: grid (N/4/256, N), each thread writes one float4
    {
        const int threads = 256;
        dim3 grid((N / 4) / threads, N);
        expand_kernel<<<grid, threads, 0, stream>>>(s, out, N);
    }
}